// Round 3
// baseline (8354.756 us; speedup 1.0000x reference)
//
#include <hip/hip_runtime.h>
#include <stdint.h>

#define T_STEPS 128
#define BATCH   512
#define OBSD    1024
#define HD      512
#define FCD     512
#define MROWS   (T_STEPS * BATCH)   // 65536
#define SCAN_BG 8                    // batch groups: 64 rows each
#define SCAN_CG 32                   // col groups: 16 h-cols each

typedef unsigned short ushort_t;
typedef __attribute__((ext_vector_type(8))) short bf16x8;
typedef __attribute__((ext_vector_type(4))) float f32x4;

__device__ inline ushort_t f2bf(float f) {
    union { float f; uint32_t u; } v; v.f = f;
    uint32_t r = v.u + 0x7FFFu + ((v.u >> 16) & 1u);
    return (ushort_t)(r >> 16);
}
__device__ inline float bf2f(ushort_t h) {
    union { uint32_t u; float f; } v; v.u = ((uint32_t)h) << 16;
    return v.f;
}
__device__ inline float fsigmoid(float x) {
    x = fminf(fmaxf(x, -30.f), 30.f);
    return 1.f / (1.f + __expf(-x));
}
__device__ inline float ftanh(float x) {
    float e = __expf(fminf(fmaxf(2.f * x, -30.f), 30.f));
    return (e - 1.f) / (e + 1.f);
}

// ---------------- weight prep: fp32 [R,C] -> bf16 [C,R] ----------------
__global__ void transpose_to_bf16(const float* __restrict__ in,
                                  ushort_t* __restrict__ out, int R, int C) {
    __shared__ float tile[32][33];
    int tx = threadIdx.x, ty = threadIdx.y;
    int c0 = blockIdx.x * 32, r0 = blockIdx.y * 32;
    for (int yy = 0; yy < 4; ++yy)
        tile[ty + 8 * yy][tx] = in[(size_t)(r0 + ty + 8 * yy) * C + c0 + tx];
    __syncthreads();
    for (int yy = 0; yy < 4; ++yy)
        out[(size_t)(c0 + ty + 8 * yy) * R + r0 + tx] = f2bf(tile[tx][ty + 8 * yy]);
}

// init: value <- bc2, barrier counters <- 0
__global__ void init_misc(float* __restrict__ v, const float* __restrict__ bc2,
                          unsigned* __restrict__ bar) {
    int i = blockIdx.x * blockDim.x + threadIdx.x;
    if (i < MROWS) v[i] = bc2[0];
    if (i < 1024) bar[i] = 0u;
}

// ---------------- generic 64x64 MFMA GEMM: C = A @ B (+epilogues) --------
template <int K, int EPI, bool AF32>
__global__ __launch_bounds__(256) void gemm64(
    const void* __restrict__ Aptr, const ushort_t* __restrict__ BT,
    const float* __restrict__ bias, ushort_t* __restrict__ Cout, int ldc,
    const float* __restrict__ wc2, float* __restrict__ value) {
    __shared__ __align__(16) ushort_t Als[64][40];
    __shared__ __align__(16) ushort_t Bls[64][40];
    int tid = threadIdx.x;
    int wave = tid >> 6, lane = tid & 63, quad = lane >> 4, l16 = lane & 15;
    int bm = blockIdx.x * 64, bn = blockIdx.y * 64;
    int lrow = tid >> 2, lk = (tid & 3) * 8;

    f32x4 acc[4];
    for (int c = 0; c < 4; ++c) acc[c] = (f32x4){0.f, 0.f, 0.f, 0.f};

    for (int k0 = 0; k0 < K; k0 += 32) {
        if constexpr (AF32) {
            const float* A = (const float*)Aptr;
            const float4* pa =
                (const float4*)&A[(size_t)(bm + lrow) * K + k0 + lk];
            float4 a0 = pa[0], a1 = pa[1];
            ushort_t* d = &Als[lrow][lk];
            d[0] = f2bf(a0.x); d[1] = f2bf(a0.y); d[2] = f2bf(a0.z); d[3] = f2bf(a0.w);
            d[4] = f2bf(a1.x); d[5] = f2bf(a1.y); d[6] = f2bf(a1.z); d[7] = f2bf(a1.w);
        } else {
            const ushort_t* A = (const ushort_t*)Aptr;
            *(bf16x8*)&Als[lrow][lk] =
                *(const bf16x8*)&A[(size_t)(bm + lrow) * K + k0 + lk];
        }
        *(bf16x8*)&Bls[lrow][lk] =
            *(const bf16x8*)&BT[(size_t)(bn + lrow) * K + k0 + lk];
        __syncthreads();
        bf16x8 a = *(const bf16x8*)&Als[16 * wave + l16][quad * 8];
        for (int c = 0; c < 4; ++c) {
            bf16x8 b = *(const bf16x8*)&Bls[16 * c + l16][quad * 8];
            acc[c] = __builtin_amdgcn_mfma_f32_16x16x32_bf16(a, b, acc[c], 0, 0, 0);
        }
        __syncthreads();
    }

    int row_l = 16 * wave + 4 * quad;
    if constexpr (EPI == 0 || EPI == 1) {
        for (int c = 0; c < 4; ++c) {
            int col = bn + 16 * c + l16;
            float bv = bias[col];
            for (int i = 0; i < 4; ++i) {
                float v = acc[c][i] + bv;
                if constexpr (EPI == 0) v = fmaxf(v, 0.f);
                Cout[(size_t)(bm + row_l + i) * ldc + col] = f2bf(v);
            }
        }
    } else {
        float s[4] = {0.f, 0.f, 0.f, 0.f};
        for (int c = 0; c < 4; ++c) {
            int col = bn + 16 * c + l16;
            float bv = bias[col], w2 = wc2[col];
            for (int i = 0; i < 4; ++i)
                s[i] += fmaxf(acc[c][i] + bv, 0.f) * w2;
        }
        for (int i = 0; i < 4; ++i) {
            float v = s[i];
            v += __shfl_xor(v, 1);
            v += __shfl_xor(v, 2);
            v += __shfl_xor(v, 4);
            v += __shfl_xor(v, 8);
            if (l16 == 0) atomicAdd(&value[bm + row_l + i], v);
        }
    }
}

// ---------------- rowwise LayerNorm over H=512, in-place on bf16 --------
__global__ __launch_bounds__(256) void ln_kernel(ushort_t* __restrict__ emb,
                                                 const float* __restrict__ scale,
                                                 const float* __restrict__ biasv) {
    int wave = threadIdx.x >> 6, lane = threadIdx.x & 63;
    size_t row = (size_t)blockIdx.x * 4 + wave;
    ushort_t* p = &emb[row * HD + lane * 8];
    bf16x8 xv = *(const bf16x8*)p;
    float x[8];
    float sum = 0.f, sq = 0.f;
    for (int j = 0; j < 8; ++j) {
        x[j] = bf2f((ushort_t)xv[j]);
        sum += x[j];
        sq += x[j] * x[j];
    }
    for (int off = 32; off > 0; off >>= 1) {
        sum += __shfl_xor(sum, off);
        sq += __shfl_xor(sq, off);
    }
    float mean = sum * (1.f / 512.f);
    float var = fmaxf(sq * (1.f / 512.f) - mean * mean, 0.f);
    float inv = rsqrtf(var + 1e-6f);
    bf16x8 ov;
    for (int j = 0; j < 8; ++j) {
        int col = lane * 8 + j;
        ov[j] = (short)f2bf((x[j] - mean) * inv * scale[col] + biasv[col]);
    }
    *(bf16x8*)p = ov;
}

// ---------------- GRU scan: persistent, 256 blocks (plain launch) -------
// Block (bg,cg): owns batch rows [bg*64, bg*64+64), h-cols [cg*16, cg*16+16).
// Wave w = M-tile (16 rows). Wh slice (48 frags = 192 VGPR) register-resident.
// fp32 h master register-resident (cols owned by fixed block forever).
// Per step: reset+publish bf16 h slice -> 32-block group barrier -> 16
// a-loads + 48 MFMAs -> gates -> update master. Double-buffered h.
// Co-residency: 256 blocks, 1 block/CU resource footprint (LDS=0,
// VGPR<=512/wave via __launch_bounds__(256,1)) on 256 CUs -> all resident.
__global__ __launch_bounds__(256, 1) void scan_coop(
    const float* __restrict__ hidden, const int* __restrict__ dones,
    const ushort_t* __restrict__ WhT, const float* __restrict__ bhn,
    const ushort_t* __restrict__ xproj, ushort_t* __restrict__ ys,
    float* __restrict__ hlast, ushort_t* __restrict__ hb0,
    ushort_t* __restrict__ hb1, unsigned* __restrict__ bar) {
    int tid = threadIdx.x;
    int wave = tid >> 6, lane = tid & 63, quad = lane >> 4, l16 = lane & 15;
    int bid = blockIdx.x;
    int bg = bid >> 5, cg = bid & 31;
    int row0 = bg * 64 + wave * 16;   // this wave's 16 batch rows
    int col0 = cg * 16;               // this block's 16 h-cols

    // ---- load Wh B-fragments into registers (constant across all steps) ----
    bf16x8 bfr[16][3];
#pragma unroll
    for (int kt = 0; kt < 16; ++kt)
#pragma unroll
        for (int g = 0; g < 3; ++g)
            bfr[kt][g] = *(const bf16x8*)&WhT[(size_t)(g * 512 + col0 + l16) * 512 +
                                             kt * 32 + quad * 8];
    // ---- fp32 master h for owned 16x16 slice (C-layout: col=l16,row=quad*4+i)
    float mast[4];
#pragma unroll
    for (int i = 0; i < 4; ++i)
        mast[i] = hidden[(size_t)(row0 + quad * 4 + i) * HD + col0 + l16];
    float bhnv = bhn[col0 + l16];

    unsigned* cnt = &bar[bg * 32];    // 128B-spaced per-group counters

    for (int t = 0; t < T_STEPS; ++t) {
        ushort_t* wbuf = (t & 1) ? hb1 : hb0;
        // phase 1: done-reset + publish bf16 slice
#pragma unroll
        for (int i = 0; i < 4; ++i) {
            int r = row0 + quad * 4 + i;
            if (dones[t * BATCH + r]) mast[i] = 0.f;
            wbuf[(size_t)r * HD + col0 + l16] = f2bf(mast[i]);
        }
        // prefetch xproj for this step (independent of barrier)
        float xr[4], xz[4], xn[4];
#pragma unroll
        for (int i = 0; i < 4; ++i) {
            size_t m = (size_t)t * BATCH + row0 + quad * 4 + i;
            const ushort_t* xp = &xproj[m * 1536 + col0 + l16];
            xr[i] = bf2f(xp[0]);
            xz[i] = bf2f(xp[512]);
            xn[i] = bf2f(xp[1024]);
        }
        // phase 2: group barrier (32 blocks sharing bg)
        __threadfence();          // release: drain + L2 writeback before arrive
        __syncthreads();
        if (tid == 0) {
            __hip_atomic_fetch_add(cnt, 1u, __ATOMIC_RELEASE,
                                   __HIP_MEMORY_SCOPE_AGENT);
            unsigned target = 32u * (unsigned)(t + 1);
            while (__hip_atomic_load(cnt, __ATOMIC_ACQUIRE,
                                     __HIP_MEMORY_SCOPE_AGENT) < target)
                __builtin_amdgcn_s_sleep(2);
        }
        __syncthreads();
        __builtin_amdgcn_fence(__ATOMIC_ACQUIRE, "agent");  // invalidate caches
        // phase 3: h @ Wh for owned cols
        f32x4 aR = (f32x4){0.f, 0.f, 0.f, 0.f};
        f32x4 aZ = (f32x4){0.f, 0.f, 0.f, 0.f};
        f32x4 aN = (f32x4){0.f, 0.f, 0.f, 0.f};
#pragma unroll
        for (int kt = 0; kt < 16; ++kt) {
            bf16x8 a = *(const bf16x8*)&wbuf[(size_t)(row0 + l16) * HD +
                                             kt * 32 + quad * 8];
            aR = __builtin_amdgcn_mfma_f32_16x16x32_bf16(a, bfr[kt][0], aR, 0, 0, 0);
            aZ = __builtin_amdgcn_mfma_f32_16x16x32_bf16(a, bfr[kt][1], aZ, 0, 0, 0);
            aN = __builtin_amdgcn_mfma_f32_16x16x32_bf16(a, bfr[kt][2], aN, 0, 0, 0);
        }
        // phase 4: gates + master update + ys
#pragma unroll
        for (int i = 0; i < 4; ++i) {
            float r = fsigmoid(xr[i] + aR[i]);
            float z = fsigmoid(xz[i] + aZ[i]);
            float n = ftanh(xn[i] + r * (aN[i] + bhnv));
            float hnew = (1.f - z) * n + z * mast[i];
            mast[i] = hnew;
            size_t m = (size_t)t * BATCH + row0 + quad * 4 + i;
            ys[m * HD + col0 + l16] = f2bf(hnew);
        }
    }
#pragma unroll
    for (int i = 0; i < 4; ++i)
        hlast[(size_t)(row0 + quad * 4 + i) * HD + col0 + l16] = mast[i];
}

extern "C" void kernel_launch(void* const* d_in, const int* in_sizes, int n_in,
                              void* d_out, int out_size, void* d_ws,
                              size_t ws_size, hipStream_t stream) {
    const float* hidden      = (const float*)d_in[0];
    const float* world_state = (const float*)d_in[1];
    const int*   dones       = (const int*)d_in[2];
    const float* Wd  = (const float*)d_in[3];
    const float* bd  = (const float*)d_in[4];
    const float* lns = (const float*)d_in[5];
    const float* lnb = (const float*)d_in[6];
    const float* Wi  = (const float*)d_in[7];
    const float* bi  = (const float*)d_in[8];
    const float* Wh  = (const float*)d_in[9];
    const float* bhn = (const float*)d_in[10];
    const float* Wc1 = (const float*)d_in[11];
    const float* bc1 = (const float*)d_in[12];
    const float* Wc2 = (const float*)d_in[13];
    const float* bc2 = (const float*)d_in[14];

    float* out_h = (float*)d_out;            // h_last [512,512]
    float* out_v = out_h + BATCH * HD;       // value  [128,512]

    char* ws = (char*)d_ws;
    ushort_t* WdT   = (ushort_t*)(ws + 0);            // [512][1024]
    ushort_t* WiT   = (ushort_t*)(ws + 1048576);      // [1536][512]
    ushort_t* WhT   = (ushort_t*)(ws + 2621440);      // [1536][512]
    ushort_t* Wc1T  = (ushort_t*)(ws + 4194304);      // [512][512]
    unsigned* bar   = (unsigned*)(ws + 4718592);      // 1024 uints
    ushort_t* hb0   = (ushort_t*)(ws + 4722688);      // [512][512] bf16
    ushort_t* hb1   = (ushort_t*)(ws + 5246976);      // [512][512] bf16
    ushort_t* xproj = (ushort_t*)(ws + 8388608);      // [65536][1536] bf16
    ushort_t* emb   = (ushort_t*)(ws + 209715200);    // [65536][512] bf16
    ushort_t* ysb   = emb;  // reuse: emb dead after gemm2, ys written by scan

    dim3 tb(32, 8);
    transpose_to_bf16<<<dim3(16, 32), tb, 0, stream>>>(Wd, WdT, OBSD, HD);
    transpose_to_bf16<<<dim3(48, 16), tb, 0, stream>>>(Wi, WiT, HD, 1536);
    transpose_to_bf16<<<dim3(48, 16), tb, 0, stream>>>(Wh, WhT, HD, 1536);
    transpose_to_bf16<<<dim3(16, 16), tb, 0, stream>>>(Wc1, Wc1T, HD, FCD);
    init_misc<<<256, 256, 0, stream>>>(out_v, bc2, bar);

    // emb = relu(world_state @ Wd + bd)
    gemm64<OBSD, 0, true><<<dim3(MROWS / 64, HD / 64), 256, 0, stream>>>(
        world_state, WdT, bd, emb, HD, nullptr, nullptr);
    // LayerNorm in place
    ln_kernel<<<MROWS / 4, 256, 0, stream>>>(emb, lns, lnb);
    // xproj = emb @ Wi + bi
    gemm64<HD, 1, false><<<dim3(MROWS / 64, 1536 / 64), 256, 0, stream>>>(
        emb, WiT, bi, xproj, 1536, nullptr, nullptr);
    // persistent GRU scan: 256 blocks (8 bg x 32 cg), register-resident Wh,
    // group barriers (co-resident by construction: 1 block/CU on 256 CUs)
    scan_coop<<<dim3(SCAN_BG * SCAN_CG), dim3(256), 0, stream>>>(
        hidden, dones, WhT, bhn, xproj, ysb, out_h, hb0, hb1, bar);
    // value = relu(ys @ Wc1 + bc1) @ Wc2 + bc2
    gemm64<HD, 2, false><<<dim3(MROWS / 64, FCD / 64), 256, 0, stream>>>(
        ysb, Wc1T, bc1, nullptr, 0, Wc2, out_v);
}

// Round 4
// 2132.787 us; speedup vs baseline: 3.9173x; 3.9173x over previous
//
#include <hip/hip_runtime.h>
#include <stdint.h>

#define T_STEPS 128
#define BATCH   512
#define OBSD    1024
#define HD      512
#define FCD     512
#define MROWS   (T_STEPS * BATCH)   // 65536
#define SCAN_BG 8                    // batch groups: 64 rows each
#define SCAN_CG 32                   // col groups: 16 h-cols each

typedef unsigned short ushort_t;
typedef __attribute__((ext_vector_type(8))) short bf16x8;
typedef __attribute__((ext_vector_type(4))) float f32x4;

__device__ inline ushort_t f2bf(float f) {
    union { float f; uint32_t u; } v; v.f = f;
    uint32_t r = v.u + 0x7FFFu + ((v.u >> 16) & 1u);
    return (ushort_t)(r >> 16);
}
__device__ inline float bf2f(ushort_t h) {
    union { uint32_t u; float f; } v; v.u = ((uint32_t)h) << 16;
    return v.f;
}
__device__ inline float fsigmoid(float x) {
    x = fminf(fmaxf(x, -30.f), 30.f);
    return 1.f / (1.f + __expf(-x));
}
__device__ inline float ftanh(float x) {
    float e = __expf(fminf(fmaxf(2.f * x, -30.f), 30.f));
    return (e - 1.f) / (e + 1.f);
}

// ---------------- weight prep: fp32 [R,C] -> bf16 [C,R] ----------------
__global__ void transpose_to_bf16(const float* __restrict__ in,
                                  ushort_t* __restrict__ out, int R, int C) {
    __shared__ float tile[32][33];
    int tx = threadIdx.x, ty = threadIdx.y;
    int c0 = blockIdx.x * 32, r0 = blockIdx.y * 32;
    for (int yy = 0; yy < 4; ++yy)
        tile[ty + 8 * yy][tx] = in[(size_t)(r0 + ty + 8 * yy) * C + c0 + tx];
    __syncthreads();
    for (int yy = 0; yy < 4; ++yy)
        out[(size_t)(c0 + ty + 8 * yy) * R + r0 + tx] = f2bf(tile[tx][ty + 8 * yy]);
}

// init: value <- bc2, barrier counters <- 0
__global__ void init_misc(float* __restrict__ v, const float* __restrict__ bc2,
                          unsigned* __restrict__ bar) {
    int i = blockIdx.x * blockDim.x + threadIdx.x;
    if (i < MROWS) v[i] = bc2[0];
    if (i < 1024) bar[i] = 0u;
}

// ---------------- generic 64x64 MFMA GEMM: C = A @ B (+epilogues) --------
template <int K, int EPI, bool AF32>
__global__ __launch_bounds__(256) void gemm64(
    const void* __restrict__ Aptr, const ushort_t* __restrict__ BT,
    const float* __restrict__ bias, ushort_t* __restrict__ Cout, int ldc,
    const float* __restrict__ wc2, float* __restrict__ value) {
    __shared__ __align__(16) ushort_t Als[64][40];
    __shared__ __align__(16) ushort_t Bls[64][40];
    int tid = threadIdx.x;
    int wave = tid >> 6, lane = tid & 63, quad = lane >> 4, l16 = lane & 15;
    int bm = blockIdx.x * 64, bn = blockIdx.y * 64;
    int lrow = tid >> 2, lk = (tid & 3) * 8;

    f32x4 acc[4];
    for (int c = 0; c < 4; ++c) acc[c] = (f32x4){0.f, 0.f, 0.f, 0.f};

    for (int k0 = 0; k0 < K; k0 += 32) {
        if constexpr (AF32) {
            const float* A = (const float*)Aptr;
            const float4* pa =
                (const float4*)&A[(size_t)(bm + lrow) * K + k0 + lk];
            float4 a0 = pa[0], a1 = pa[1];
            ushort_t* d = &Als[lrow][lk];
            d[0] = f2bf(a0.x); d[1] = f2bf(a0.y); d[2] = f2bf(a0.z); d[3] = f2bf(a0.w);
            d[4] = f2bf(a1.x); d[5] = f2bf(a1.y); d[6] = f2bf(a1.z); d[7] = f2bf(a1.w);
        } else {
            const ushort_t* A = (const ushort_t*)Aptr;
            *(bf16x8*)&Als[lrow][lk] =
                *(const bf16x8*)&A[(size_t)(bm + lrow) * K + k0 + lk];
        }
        *(bf16x8*)&Bls[lrow][lk] =
            *(const bf16x8*)&BT[(size_t)(bn + lrow) * K + k0 + lk];
        __syncthreads();
        bf16x8 a = *(const bf16x8*)&Als[16 * wave + l16][quad * 8];
        for (int c = 0; c < 4; ++c) {
            bf16x8 b = *(const bf16x8*)&Bls[16 * c + l16][quad * 8];
            acc[c] = __builtin_amdgcn_mfma_f32_16x16x32_bf16(a, b, acc[c], 0, 0, 0);
        }
        __syncthreads();
    }

    int row_l = 16 * wave + 4 * quad;
    if constexpr (EPI == 0 || EPI == 1) {
        for (int c = 0; c < 4; ++c) {
            int col = bn + 16 * c + l16;
            float bv = bias[col];
            for (int i = 0; i < 4; ++i) {
                float v = acc[c][i] + bv;
                if constexpr (EPI == 0) v = fmaxf(v, 0.f);
                Cout[(size_t)(bm + row_l + i) * ldc + col] = f2bf(v);
            }
        }
    } else {
        float s[4] = {0.f, 0.f, 0.f, 0.f};
        for (int c = 0; c < 4; ++c) {
            int col = bn + 16 * c + l16;
            float bv = bias[col], w2 = wc2[col];
            for (int i = 0; i < 4; ++i)
                s[i] += fmaxf(acc[c][i] + bv, 0.f) * w2;
        }
        for (int i = 0; i < 4; ++i) {
            float v = s[i];
            v += __shfl_xor(v, 1);
            v += __shfl_xor(v, 2);
            v += __shfl_xor(v, 4);
            v += __shfl_xor(v, 8);
            if (l16 == 0) atomicAdd(&value[bm + row_l + i], v);
        }
    }
}

// ---------------- rowwise LayerNorm over H=512, in-place on bf16 --------
__global__ __launch_bounds__(256) void ln_kernel(ushort_t* __restrict__ emb,
                                                 const float* __restrict__ scale,
                                                 const float* __restrict__ biasv) {
    int wave = threadIdx.x >> 6, lane = threadIdx.x & 63;
    size_t row = (size_t)blockIdx.x * 4 + wave;
    ushort_t* p = &emb[row * HD + lane * 8];
    bf16x8 xv = *(const bf16x8*)p;
    float x[8];
    float sum = 0.f, sq = 0.f;
    for (int j = 0; j < 8; ++j) {
        x[j] = bf2f((ushort_t)xv[j]);
        sum += x[j];
        sq += x[j] * x[j];
    }
    for (int off = 32; off > 0; off >>= 1) {
        sum += __shfl_xor(sum, off);
        sq += __shfl_xor(sq, off);
    }
    float mean = sum * (1.f / 512.f);
    float var = fmaxf(sq * (1.f / 512.f) - mean * mean, 0.f);
    float inv = rsqrtf(var + 1e-6f);
    bf16x8 ov;
    for (int j = 0; j < 8; ++j) {
        int col = lane * 8 + j;
        ov[j] = (short)f2bf((x[j] - mean) * inv * scale[col] + biasv[col]);
    }
    *(bf16x8*)p = ov;
}

// ---------------- GRU scan: persistent, 256 blocks, fence-free ----------
// Block (bg,cg): owns batch rows [bg*64,+64), h-cols [cg*16,+16).
// Wh slice register-resident (pinned via asm). fp32 h master in registers.
// h ping-pong exchanged ONLY via relaxed agent-scope atomics (sc1: bypass
// non-coherent per-XCD L2, hit coherent L3) -> no wbl2/inv cache maintenance.
// Ordering: stores -> s_waitcnt(0) -> syncthreads -> relaxed RMW arrive;
// consumer: relaxed poll -> branch dep + compiler barrier -> sc1 loads.
__global__ __launch_bounds__(256, 1) void scan_coop(
    const float* __restrict__ hidden, const int* __restrict__ dones,
    const ushort_t* __restrict__ WhT, const float* __restrict__ bhn,
    const ushort_t* __restrict__ xproj, ushort_t* __restrict__ ys,
    float* __restrict__ hlast, ushort_t* hb0, ushort_t* hb1,
    unsigned* bar) {
    int tid = threadIdx.x;
    int wave = tid >> 6, lane = tid & 63, quad = lane >> 4, l16 = lane & 15;
    int bid = blockIdx.x;
    int bg = bid >> 5, cg = bid & 31;
    int row0 = bg * 64 + wave * 16;   // this wave's 16 batch rows
    int col0 = cg * 16;               // this block's 16 h-cols

    // ---- load Wh B-fragments into registers; pin so compiler can't sink ----
    bf16x8 bfr[16][3];
#pragma unroll
    for (int kt = 0; kt < 16; ++kt)
#pragma unroll
        for (int g = 0; g < 3; ++g)
            bfr[kt][g] = *(const bf16x8*)&WhT[(size_t)(g * 512 + col0 + l16) * 512 +
                                             kt * 32 + quad * 8];
#pragma unroll
    for (int kt = 0; kt < 16; ++kt)
#pragma unroll
        for (int g = 0; g < 3; ++g)
            asm volatile("" : "+v"(bfr[kt][g]));

    // ---- fp32 master h for owned 16x16 slice (C-layout: col=l16,row=quad*4+i)
    float mast[4];
#pragma unroll
    for (int i = 0; i < 4; ++i)
        mast[i] = hidden[(size_t)(row0 + quad * 4 + i) * HD + col0 + l16];
    float bhnv = bhn[col0 + l16];

    unsigned* cnt = &bar[bg * 32];    // 128B-spaced per-group counters

    for (int t = 0; t < T_STEPS; ++t) {
        ushort_t* wbuf = (t & 1) ? hb1 : hb0;
        // phase 1: done-reset + publish bf16 slice (pack 4 cols -> 8B store)
#pragma unroll
        for (int i = 0; i < 4; ++i) {
            int r = row0 + quad * 4 + i;
            if (dones[t * BATCH + r]) mast[i] = 0.f;
            unsigned u = f2bf(mast[i]);
            unsigned p1 = __shfl_xor((int)u, 1);
            unsigned u32 = u | (p1 << 16);
            unsigned hi = __shfl_xor((int)u32, 2);
            if ((l16 & 3) == 0) {
                unsigned long long q =
                    (unsigned long long)u32 | ((unsigned long long)hi << 32);
                __hip_atomic_store(
                    (unsigned long long*)&wbuf[(size_t)r * HD + col0 + l16], q,
                    __ATOMIC_RELAXED, __HIP_MEMORY_SCOPE_AGENT);
            }
        }
        // prefetch xproj for this step (independent of barrier)
        float xr[4], xz[4], xn[4];
#pragma unroll
        for (int i = 0; i < 4; ++i) {
            size_t m = (size_t)t * BATCH + row0 + quad * 4 + i;
            const ushort_t* xp = &xproj[m * 1536 + col0 + l16];
            xr[i] = bf2f(xp[0]);
            xz[i] = bf2f(xp[512]);
            xn[i] = bf2f(xp[1024]);
        }
        // phase 2: group barrier (32 blocks sharing bg) — no cache fences.
        __builtin_amdgcn_s_waitcnt(0);   // sc1 stores acked at coherent point
        __syncthreads();
        if (tid == 0) {
            __hip_atomic_fetch_add(cnt, 1u, __ATOMIC_RELAXED,
                                   __HIP_MEMORY_SCOPE_AGENT);
            unsigned target = 32u * (unsigned)(t + 1);
            while (__hip_atomic_load(cnt, __ATOMIC_RELAXED,
                                     __HIP_MEMORY_SCOPE_AGENT) < target)
                __builtin_amdgcn_s_sleep(2);
        }
        __syncthreads();
        asm volatile("" ::: "memory");   // no hoisting of a-loads above poll
        // phase 3: gather a-frags (independent sc1 loads), then MFMA
        bf16x8 afr[16];
#pragma unroll
        for (int kt = 0; kt < 16; ++kt) {
            unsigned long long* ap =
                (unsigned long long*)&wbuf[(size_t)(row0 + l16) * HD +
                                           kt * 32 + quad * 8];
            unsigned long long q0 = __hip_atomic_load(
                ap, __ATOMIC_RELAXED, __HIP_MEMORY_SCOPE_AGENT);
            unsigned long long q1 = __hip_atomic_load(
                ap + 1, __ATOMIC_RELAXED, __HIP_MEMORY_SCOPE_AGENT);
            union { unsigned long long u[2]; bf16x8 v; } cvt;
            cvt.u[0] = q0; cvt.u[1] = q1;
            afr[kt] = cvt.v;
        }
        f32x4 aR = (f32x4){0.f, 0.f, 0.f, 0.f};
        f32x4 aZ = (f32x4){0.f, 0.f, 0.f, 0.f};
        f32x4 aN = (f32x4){0.f, 0.f, 0.f, 0.f};
#pragma unroll
        for (int kt = 0; kt < 16; ++kt) {
            aR = __builtin_amdgcn_mfma_f32_16x16x32_bf16(afr[kt], bfr[kt][0], aR, 0, 0, 0);
            aZ = __builtin_amdgcn_mfma_f32_16x16x32_bf16(afr[kt], bfr[kt][1], aZ, 0, 0, 0);
            aN = __builtin_amdgcn_mfma_f32_16x16x32_bf16(afr[kt], bfr[kt][2], aN, 0, 0, 0);
        }
        // phase 4: gates + master update + ys
#pragma unroll
        for (int i = 0; i < 4; ++i) {
            float r = fsigmoid(xr[i] + aR[i]);
            float z = fsigmoid(xz[i] + aZ[i]);
            float n = ftanh(xn[i] + r * (aN[i] + bhnv));
            float hnew = (1.f - z) * n + z * mast[i];
            mast[i] = hnew;
            size_t m = (size_t)t * BATCH + row0 + quad * 4 + i;
            ys[m * HD + col0 + l16] = f2bf(hnew);
        }
    }
#pragma unroll
    for (int i = 0; i < 4; ++i)
        hlast[(size_t)(row0 + quad * 4 + i) * HD + col0 + l16] = mast[i];
}

extern "C" void kernel_launch(void* const* d_in, const int* in_sizes, int n_in,
                              void* d_out, int out_size, void* d_ws,
                              size_t ws_size, hipStream_t stream) {
    const float* hidden      = (const float*)d_in[0];
    const float* world_state = (const float*)d_in[1];
    const int*   dones       = (const int*)d_in[2];
    const float* Wd  = (const float*)d_in[3];
    const float* bd  = (const float*)d_in[4];
    const float* lns = (const float*)d_in[5];
    const float* lnb = (const float*)d_in[6];
    const float* Wi  = (const float*)d_in[7];
    const float* bi  = (const float*)d_in[8];
    const float* Wh  = (const float*)d_in[9];
    const float* bhn = (const float*)d_in[10];
    const float* Wc1 = (const float*)d_in[11];
    const float* bc1 = (const float*)d_in[12];
    const float* Wc2 = (const float*)d_in[13];
    const float* bc2 = (const float*)d_in[14];

    float* out_h = (float*)d_out;            // h_last [512,512]
    float* out_v = out_h + BATCH * HD;       // value  [128,512]

    char* ws = (char*)d_ws;
    ushort_t* WdT   = (ushort_t*)(ws + 0);            // [512][1024]
    ushort_t* WiT   = (ushort_t*)(ws + 1048576);      // [1536][512]
    ushort_t* WhT   = (ushort_t*)(ws + 2621440);      // [1536][512]
    ushort_t* Wc1T  = (ushort_t*)(ws + 4194304);      // [512][512]
    unsigned* bar   = (unsigned*)(ws + 4718592);      // 1024 uints
    ushort_t* hb0   = (ushort_t*)(ws + 4722688);      // [512][512] bf16
    ushort_t* hb1   = (ushort_t*)(ws + 5246976);      // [512][512] bf16
    ushort_t* xproj = (ushort_t*)(ws + 8388608);      // [65536][1536] bf16
    ushort_t* emb   = (ushort_t*)(ws + 209715200);    // [65536][512] bf16
    ushort_t* ysb   = emb;  // reuse: emb dead after gemm2, ys written by scan

    dim3 tb(32, 8);
    transpose_to_bf16<<<dim3(16, 32), tb, 0, stream>>>(Wd, WdT, OBSD, HD);
    transpose_to_bf16<<<dim3(48, 16), tb, 0, stream>>>(Wi, WiT, HD, 1536);
    transpose_to_bf16<<<dim3(48, 16), tb, 0, stream>>>(Wh, WhT, HD, 1536);
    transpose_to_bf16<<<dim3(16, 16), tb, 0, stream>>>(Wc1, Wc1T, HD, FCD);
    init_misc<<<256, 256, 0, stream>>>(out_v, bc2, bar);

    // emb = relu(world_state @ Wd + bd)
    gemm64<OBSD, 0, true><<<dim3(MROWS / 64, HD / 64), 256, 0, stream>>>(
        world_state, WdT, bd, emb, HD, nullptr, nullptr);
    // LayerNorm in place
    ln_kernel<<<MROWS / 4, 256, 0, stream>>>(emb, lns, lnb);
    // xproj = emb @ Wi + bi
    gemm64<HD, 1, false><<<dim3(MROWS / 64, 1536 / 64), 256, 0, stream>>>(
        emb, WiT, bi, xproj, 1536, nullptr, nullptr);
    // persistent GRU scan: 256 blocks (8 bg x 32 cg), register-resident Wh,
    // fence-free group barriers (co-resident: 1 block/CU min on 256 CUs)
    scan_coop<<<dim3(SCAN_BG * SCAN_CG), dim3(256), 0, stream>>>(
        hidden, dones, WhT, bhn, xproj, ysb, out_h, hb0, hb1, bar);
    // value = relu(ys @ Wc1 + bc1) @ Wc2 + bc2
    gemm64<HD, 2, false><<<dim3(MROWS / 64, FCD / 64), 256, 0, stream>>>(
        ysb, Wc1T, bc1, nullptr, 0, Wc2, out_v);
}

// Round 5
// 1844.784 us; speedup vs baseline: 4.5289x; 1.1561x over previous
//
#include <hip/hip_runtime.h>
#include <stdint.h>

#define T_STEPS 128
#define BATCH   512
#define OBSD    1024
#define HD      512
#define FCD     512
#define MROWS   (T_STEPS * BATCH)   // 65536

typedef unsigned short ushort_t;
typedef __attribute__((ext_vector_type(8))) short bf16x8;
typedef __attribute__((ext_vector_type(4))) float f32x4;

__device__ inline ushort_t f2bf(float f) {
    union { float f; uint32_t u; } v; v.f = f;
    uint32_t r = v.u + 0x7FFFu + ((v.u >> 16) & 1u);
    return (ushort_t)(r >> 16);
}
__device__ inline float bf2f(ushort_t h) {
    union { uint32_t u; float f; } v; v.u = ((uint32_t)h) << 16;
    return v.f;
}
__device__ inline float fsigmoid(float x) {
    x = fminf(fmaxf(x, -30.f), 30.f);
    return 1.f / (1.f + __expf(-x));
}
__device__ inline float ftanh(float x) {
    float e = __expf(fminf(fmaxf(2.f * x, -30.f), 30.f));
    return (e - 1.f) / (e + 1.f);
}

// ---------------- weight prep: fp32 [R,C] -> bf16 [C,R] ----------------
__global__ void transpose_to_bf16(const float* __restrict__ in,
                                  ushort_t* __restrict__ out, int R, int C) {
    __shared__ float tile[32][33];
    int tx = threadIdx.x, ty = threadIdx.y;
    int c0 = blockIdx.x * 32, r0 = blockIdx.y * 32;
    for (int yy = 0; yy < 4; ++yy)
        tile[ty + 8 * yy][tx] = in[(size_t)(r0 + ty + 8 * yy) * C + c0 + tx];
    __syncthreads();
    for (int yy = 0; yy < 4; ++yy)
        out[(size_t)(c0 + ty + 8 * yy) * R + r0 + tx] = f2bf(tile[tx][ty + 8 * yy]);
}

// init: value <- bc2, barrier counters <- 0
__global__ void init_misc(float* __restrict__ v, const float* __restrict__ bc2,
                          unsigned* __restrict__ bar) {
    int i = blockIdx.x * blockDim.x + threadIdx.x;
    if (i < MROWS) v[i] = bc2[0];
    if (i < 2048) bar[i] = 0u;
}

// ---------------- generic 64x64 MFMA GEMM: C = A @ B (+epilogues) --------
template <int K, int EPI, bool AF32>
__global__ __launch_bounds__(256) void gemm64(
    const void* __restrict__ Aptr, const ushort_t* __restrict__ BT,
    const float* __restrict__ bias, ushort_t* __restrict__ Cout, int ldc,
    const float* __restrict__ wc2, float* __restrict__ value) {
    __shared__ __align__(16) ushort_t Als[64][40];
    __shared__ __align__(16) ushort_t Bls[64][40];
    int tid = threadIdx.x;
    int wave = tid >> 6, lane = tid & 63, quad = lane >> 4, l16 = lane & 15;
    int bm = blockIdx.x * 64, bn = blockIdx.y * 64;
    int lrow = tid >> 2, lk = (tid & 3) * 8;

    f32x4 acc[4];
    for (int c = 0; c < 4; ++c) acc[c] = (f32x4){0.f, 0.f, 0.f, 0.f};

    for (int k0 = 0; k0 < K; k0 += 32) {
        if constexpr (AF32) {
            const float* A = (const float*)Aptr;
            const float4* pa =
                (const float4*)&A[(size_t)(bm + lrow) * K + k0 + lk];
            float4 a0 = pa[0], a1 = pa[1];
            ushort_t* d = &Als[lrow][lk];
            d[0] = f2bf(a0.x); d[1] = f2bf(a0.y); d[2] = f2bf(a0.z); d[3] = f2bf(a0.w);
            d[4] = f2bf(a1.x); d[5] = f2bf(a1.y); d[6] = f2bf(a1.z); d[7] = f2bf(a1.w);
        } else {
            const ushort_t* A = (const ushort_t*)Aptr;
            *(bf16x8*)&Als[lrow][lk] =
                *(const bf16x8*)&A[(size_t)(bm + lrow) * K + k0 + lk];
        }
        *(bf16x8*)&Bls[lrow][lk] =
            *(const bf16x8*)&BT[(size_t)(bn + lrow) * K + k0 + lk];
        __syncthreads();
        bf16x8 a = *(const bf16x8*)&Als[16 * wave + l16][quad * 8];
        for (int c = 0; c < 4; ++c) {
            bf16x8 b = *(const bf16x8*)&Bls[16 * c + l16][quad * 8];
            acc[c] = __builtin_amdgcn_mfma_f32_16x16x32_bf16(a, b, acc[c], 0, 0, 0);
        }
        __syncthreads();
    }

    int row_l = 16 * wave + 4 * quad;
    if constexpr (EPI == 0 || EPI == 1) {
        for (int c = 0; c < 4; ++c) {
            int col = bn + 16 * c + l16;
            float bv = bias[col];
            for (int i = 0; i < 4; ++i) {
                float v = acc[c][i] + bv;
                if constexpr (EPI == 0) v = fmaxf(v, 0.f);
                Cout[(size_t)(bm + row_l + i) * ldc + col] = f2bf(v);
            }
        }
    } else {
        float s[4] = {0.f, 0.f, 0.f, 0.f};
        for (int c = 0; c < 4; ++c) {
            int col = bn + 16 * c + l16;
            float bv = bias[col], w2 = wc2[col];
            for (int i = 0; i < 4; ++i)
                s[i] += fmaxf(acc[c][i] + bv, 0.f) * w2;
        }
        for (int i = 0; i < 4; ++i) {
            float v = s[i];
            v += __shfl_xor(v, 1);
            v += __shfl_xor(v, 2);
            v += __shfl_xor(v, 4);
            v += __shfl_xor(v, 8);
            if (l16 == 0) atomicAdd(&value[bm + row_l + i], v);
        }
    }
}

// ---------------- rowwise LayerNorm over H=512, in-place on bf16 --------
__global__ __launch_bounds__(256) void ln_kernel(ushort_t* __restrict__ emb,
                                                 const float* __restrict__ scale,
                                                 const float* __restrict__ biasv) {
    int wave = threadIdx.x >> 6, lane = threadIdx.x & 63;
    size_t row = (size_t)blockIdx.x * 4 + wave;
    ushort_t* p = &emb[row * HD + lane * 8];
    bf16x8 xv = *(const bf16x8*)p;
    float x[8];
    float sum = 0.f, sq = 0.f;
    for (int j = 0; j < 8; ++j) {
        x[j] = bf2f((ushort_t)xv[j]);
        sum += x[j];
        sq += x[j] * x[j];
    }
    for (int off = 32; off > 0; off >>= 1) {
        sum += __shfl_xor(sum, off);
        sq += __shfl_xor(sq, off);
    }
    float mean = sum * (1.f / 512.f);
    float var = fmaxf(sq * (1.f / 512.f) - mean * mean, 0.f);
    float inv = rsqrtf(var + 1e-6f);
    bf16x8 ov;
    for (int j = 0; j < 8; ++j) {
        int col = lane * 8 + j;
        ov[j] = (short)f2bf((x[j] - mean) * inv * scale[col] + biasv[col]);
    }
    *(bf16x8*)p = ov;
}

// ---------------- GRU scan: persistent 256 blocks, LDS Wh, fence-free ---
// bg = bid&7 (XCD-local groups under bid%8 heuristic), cg = bid>>3.
// Block owns rows [bg*64,+64) x cols [cg*16,+16). Wh slice in LDS
// (48 x 520-short padded rows: bank-step 4 => conflict-free b128 reads).
// h ping-pong via relaxed agent-scope sc1 atomics (bypass per-XCD L2).
// Pipeline: publish(t+1) in phase 4 w/ prefetched dones; waitcnt drains only
// publishes; ys + next prefetch issue after drain, overlap next poll.
// Barrier: 8 sub-counters x 4 arrivals, poller sums.
__global__ __launch_bounds__(256, 1) void scan_coop(
    const float* __restrict__ hidden, const int* __restrict__ dones,
    const ushort_t* __restrict__ WhT, const float* __restrict__ bhn,
    const ushort_t* __restrict__ xproj, ushort_t* __restrict__ ys,
    float* __restrict__ hlast, ushort_t* hb0, ushort_t* hb1,
    unsigned* bar) {
    __shared__ __align__(16) ushort_t Wls[48][520];   // 49,920 B
    int tid = threadIdx.x;
    int wave = tid >> 6, lane = tid & 63, quad = lane >> 4, l16 = lane & 15;
    int bid = blockIdx.x;
    int bg = bid & 7, cg = bid >> 3;
    int row0 = bg * 64 + wave * 16;   // this wave's 16 batch rows
    int col0 = cg * 16;               // this block's 16 h-cols

    // ---- stage Wh slice into LDS: row c = gate(c>>4), local col (c&15) ----
    for (int idx = tid; idx < 48 * 64; idx += 256) {
        int c = idx >> 6, ck = (idx & 63) * 8;
        int g = c >> 4, lc = c & 15;
        *(bf16x8*)&Wls[c][ck] =
            *(const bf16x8*)&WhT[(size_t)(g * 512 + col0 + lc) * 512 + ck];
    }

    // ---- fp32 master h (C-layout: col=l16, row=quad*4+i), done(0)-masked --
    float mast[4];
    int rbase = row0 + quad * 4;
#pragma unroll
    for (int i = 0; i < 4; ++i) {
        float h0 = hidden[(size_t)(rbase + i) * HD + col0 + l16];
        mast[i] = dones[rbase + i] ? 0.f : h0;   // dones[0*BATCH + r]
    }
    float bhnv = bhn[col0 + l16];

    unsigned* cnt = &bar[bg * 256];   // 8 sub-counters, 128 B apart
    unsigned* mycnt = &cnt[(cg & 7) * 32];

    // ---- publish(0) into hb0 ----
#pragma unroll
    for (int i = 0; i < 4; ++i) {
        unsigned u = f2bf(mast[i]);
        unsigned p1 = __shfl_xor((int)u, 1);
        unsigned u32 = u | (p1 << 16);
        unsigned hi = __shfl_xor((int)u32, 2);
        if ((l16 & 3) == 0) {
            unsigned long long q =
                (unsigned long long)u32 | ((unsigned long long)hi << 32);
            __hip_atomic_store(
                (unsigned long long*)&hb0[(size_t)(rbase + i) * HD + col0 + l16],
                q, __ATOMIC_RELAXED, __HIP_MEMORY_SCOPE_AGENT);
        }
    }
    // prefetch xproj(0) and dones(1)
    float xr[4], xz[4], xn[4];
    int dn_nxt[4];
#pragma unroll
    for (int i = 0; i < 4; ++i) {
        size_t m = (size_t)(rbase + i);
        const ushort_t* xp = &xproj[m * 1536 + col0 + l16];
        xr[i] = bf2f(xp[0]);
        xz[i] = bf2f(xp[512]);
        xn[i] = bf2f(xp[1024]);
        dn_nxt[i] = dones[BATCH + rbase + i];
    }
    __builtin_amdgcn_s_waitcnt(0);   // publishes acked at coherent pt; LDS done
    __syncthreads();
    if (tid == 0)
        __hip_atomic_fetch_add(mycnt, 1u, __ATOMIC_RELAXED,
                               __HIP_MEMORY_SCOPE_AGENT);

    for (int t = 0; t < T_STEPS; ++t) {
        // ---- barrier wait: all 32 group blocks published step t ----
        if (tid == 0) {
            unsigned target = 32u * (unsigned)(t + 1);
            for (;;) {
                unsigned s = 0;
#pragma unroll
                for (int c = 0; c < 8; ++c)
                    s += __hip_atomic_load(&cnt[c * 32], __ATOMIC_RELAXED,
                                           __HIP_MEMORY_SCOPE_AGENT);
                if (s >= target) break;
                __builtin_amdgcn_s_sleep(1);
            }
        }
        __syncthreads();
        asm volatile("" ::: "memory");
        ushort_t* rbuf = (t & 1) ? hb1 : hb0;
        ushort_t* wnext = (t & 1) ? hb0 : hb1;

        // ---- a-frags (independent sc1 loads), b-frags from LDS, MFMA ----
        bf16x8 afr[16];
#pragma unroll
        for (int kt = 0; kt < 16; ++kt) {
            unsigned long long* ap =
                (unsigned long long*)&rbuf[(size_t)(row0 + l16) * HD +
                                           kt * 32 + quad * 8];
            unsigned long long q0 = __hip_atomic_load(
                ap, __ATOMIC_RELAXED, __HIP_MEMORY_SCOPE_AGENT);
            unsigned long long q1 = __hip_atomic_load(
                ap + 1, __ATOMIC_RELAXED, __HIP_MEMORY_SCOPE_AGENT);
            union { unsigned long long u[2]; bf16x8 v; } cvt;
            cvt.u[0] = q0; cvt.u[1] = q1;
            afr[kt] = cvt.v;
        }
        f32x4 aR = (f32x4){0.f, 0.f, 0.f, 0.f};
        f32x4 aZ = (f32x4){0.f, 0.f, 0.f, 0.f};
        f32x4 aN = (f32x4){0.f, 0.f, 0.f, 0.f};
#pragma unroll
        for (int kt = 0; kt < 16; ++kt) {
            bf16x8 bR = *(const bf16x8*)&Wls[l16][kt * 32 + quad * 8];
            bf16x8 bZ = *(const bf16x8*)&Wls[16 + l16][kt * 32 + quad * 8];
            bf16x8 bN = *(const bf16x8*)&Wls[32 + l16][kt * 32 + quad * 8];
            aR = __builtin_amdgcn_mfma_f32_16x16x32_bf16(afr[kt], bR, aR, 0, 0, 0);
            aZ = __builtin_amdgcn_mfma_f32_16x16x32_bf16(afr[kt], bZ, aZ, 0, 0, 0);
            aN = __builtin_amdgcn_mfma_f32_16x16x32_bf16(afr[kt], bN, aN, 0, 0, 0);
        }

        // ---- gates + master update; publish(t+1) with dones(t+1) mask ----
        float hnew[4];
#pragma unroll
        for (int i = 0; i < 4; ++i) {
            float r = fsigmoid(xr[i] + aR[i]);
            float z = fsigmoid(xz[i] + aZ[i]);
            float n = ftanh(xn[i] + r * (aN[i] + bhnv));
            hnew[i] = (1.f - z) * n + z * mast[i];
            mast[i] = (t < T_STEPS - 1 && dn_nxt[i]) ? 0.f : hnew[i];
        }
        if (t < T_STEPS - 1) {
#pragma unroll
            for (int i = 0; i < 4; ++i) {
                unsigned u = f2bf(mast[i]);
                unsigned p1 = __shfl_xor((int)u, 1);
                unsigned u32 = u | (p1 << 16);
                unsigned hi = __shfl_xor((int)u32, 2);
                if ((l16 & 3) == 0) {
                    unsigned long long q =
                        (unsigned long long)u32 | ((unsigned long long)hi << 32);
                    __hip_atomic_store(
                        (unsigned long long*)&wnext[(size_t)(rbase + i) * HD +
                                                    col0 + l16],
                        q, __ATOMIC_RELAXED, __HIP_MEMORY_SCOPE_AGENT);
                }
            }
        }
        asm volatile("" ::: "memory");
        __builtin_amdgcn_s_waitcnt(0);   // drain publishes (only)
        // ---- ys stores + next-step prefetch: overlap the next poll ----
#pragma unroll
        for (int i = 0; i < 4; ++i) {
            size_t m = (size_t)t * BATCH + rbase + i;
            ys[m * HD + col0 + l16] = f2bf(hnew[i]);
        }
        if (t < T_STEPS - 1) {
            int tn = t + 1;
            int td = (t + 2 < T_STEPS) ? t + 2 : T_STEPS - 1;
#pragma unroll
            for (int i = 0; i < 4; ++i) {
                size_t m = (size_t)tn * BATCH + rbase + i;
                const ushort_t* xp = &xproj[m * 1536 + col0 + l16];
                xr[i] = bf2f(xp[0]);
                xz[i] = bf2f(xp[512]);
                xn[i] = bf2f(xp[1024]);
                dn_nxt[i] = dones[td * BATCH + rbase + i];
            }
        }
        asm volatile("" ::: "memory");   // pin prefetch above arrive/poll
        __syncthreads();
        if (tid == 0 && t < T_STEPS - 1)
            __hip_atomic_fetch_add(mycnt, 1u, __ATOMIC_RELAXED,
                                   __HIP_MEMORY_SCOPE_AGENT);
    }
#pragma unroll
    for (int i = 0; i < 4; ++i)
        hlast[(size_t)(rbase + i) * HD + col0 + l16] = mast[i];
}

extern "C" void kernel_launch(void* const* d_in, const int* in_sizes, int n_in,
                              void* d_out, int out_size, void* d_ws,
                              size_t ws_size, hipStream_t stream) {
    const float* hidden      = (const float*)d_in[0];
    const float* world_state = (const float*)d_in[1];
    const int*   dones       = (const int*)d_in[2];
    const float* Wd  = (const float*)d_in[3];
    const float* bd  = (const float*)d_in[4];
    const float* lns = (const float*)d_in[5];
    const float* lnb = (const float*)d_in[6];
    const float* Wi  = (const float*)d_in[7];
    const float* bi  = (const float*)d_in[8];
    const float* Wh  = (const float*)d_in[9];
    const float* bhn = (const float*)d_in[10];
    const float* Wc1 = (const float*)d_in[11];
    const float* bc1 = (const float*)d_in[12];
    const float* Wc2 = (const float*)d_in[13];
    const float* bc2 = (const float*)d_in[14];

    float* out_h = (float*)d_out;            // h_last [512,512]
    float* out_v = out_h + BATCH * HD;       // value  [128,512]

    char* ws = (char*)d_ws;
    ushort_t* WdT   = (ushort_t*)(ws + 0);            // [512][1024]
    ushort_t* WiT   = (ushort_t*)(ws + 1048576);      // [1536][512]
    ushort_t* WhT   = (ushort_t*)(ws + 2621440);      // [1536][512]
    ushort_t* Wc1T  = (ushort_t*)(ws + 4194304);      // [512][512]
    unsigned* bar   = (unsigned*)(ws + 4718592);      // 2048 uints (8 KB)
    ushort_t* hb0   = (ushort_t*)(ws + 4726784);      // [512][512] bf16
    ushort_t* hb1   = (ushort_t*)(ws + 5251072);      // [512][512] bf16
    ushort_t* xproj = (ushort_t*)(ws + 8388608);      // [65536][1536] bf16
    ushort_t* emb   = (ushort_t*)(ws + 209715200);    // [65536][512] bf16
    ushort_t* ysb   = emb;  // reuse: emb dead after gemm2, ys written by scan

    dim3 tb(32, 8);
    transpose_to_bf16<<<dim3(16, 32), tb, 0, stream>>>(Wd, WdT, OBSD, HD);
    transpose_to_bf16<<<dim3(48, 16), tb, 0, stream>>>(Wi, WiT, HD, 1536);
    transpose_to_bf16<<<dim3(48, 16), tb, 0, stream>>>(Wh, WhT, HD, 1536);
    transpose_to_bf16<<<dim3(16, 16), tb, 0, stream>>>(Wc1, Wc1T, HD, FCD);
    init_misc<<<256, 256, 0, stream>>>(out_v, bc2, bar);

    // emb = relu(world_state @ Wd + bd)
    gemm64<OBSD, 0, true><<<dim3(MROWS / 64, HD / 64), 256, 0, stream>>>(
        world_state, WdT, bd, emb, HD, nullptr, nullptr);
    // LayerNorm in place
    ln_kernel<<<MROWS / 4, 256, 0, stream>>>(emb, lns, lnb);
    // xproj = emb @ Wi + bi
    gemm64<HD, 1, false><<<dim3(MROWS / 64, 1536 / 64), 256, 0, stream>>>(
        emb, WiT, bi, xproj, 1536, nullptr, nullptr);
    // persistent GRU scan: 256 blocks, bg=bid&7 XCD-local groups, LDS Wh
    scan_coop<<<dim3(256), dim3(256), 0, stream>>>(
        hidden, dones, WhT, bhn, xproj, ysb, out_h, hb0, hb1, bar);
    // value = relu(ys @ Wc1 + bc1) @ Wc2 + bc2
    gemm64<HD, 2, false><<<dim3(MROWS / 64, FCD / 64), 256, 0, stream>>>(
        ysb, Wc1T, bc1, nullptr, 0, Wc2, out_v);
}

// Round 6
// 1705.592 us; speedup vs baseline: 4.8985x; 1.0816x over previous
//
#include <hip/hip_runtime.h>
#include <stdint.h>

#define T_STEPS 128
#define BATCH   512
#define OBSD    1024
#define HD      512
#define FCD     512
#define MROWS   (T_STEPS * BATCH)   // 65536

typedef unsigned short ushort_t;
typedef __attribute__((ext_vector_type(8))) short bf16x8;
typedef __attribute__((ext_vector_type(4))) float f32x4;

__device__ inline ushort_t f2bf(float f) {
    union { float f; uint32_t u; } v; v.f = f;
    uint32_t r = v.u + 0x7FFFu + ((v.u >> 16) & 1u);
    return (ushort_t)(r >> 16);
}
__device__ inline float bf2f(ushort_t h) {
    union { uint32_t u; float f; } v; v.u = ((uint32_t)h) << 16;
    return v.f;
}
__device__ inline float fsigmoid(float x) {
    x = fminf(fmaxf(x, -30.f), 30.f);
    return 1.f / (1.f + __expf(-x));
}
__device__ inline float ftanh(float x) {
    float e = __expf(fminf(fmaxf(2.f * x, -30.f), 30.f));
    return (e - 1.f) / (e + 1.f);
}

// ---------------- weight prep: fp32 [R,C] -> bf16 [C,R] ----------------
__global__ void transpose_to_bf16(const float* __restrict__ in,
                                  ushort_t* __restrict__ out, int R, int C) {
    __shared__ float tile[32][33];
    int tx = threadIdx.x, ty = threadIdx.y;
    int c0 = blockIdx.x * 32, r0 = blockIdx.y * 32;
    for (int yy = 0; yy < 4; ++yy)
        tile[ty + 8 * yy][tx] = in[(size_t)(r0 + ty + 8 * yy) * C + c0 + tx];
    __syncthreads();
    for (int yy = 0; yy < 4; ++yy)
        out[(size_t)(c0 + ty + 8 * yy) * R + r0 + tx] = f2bf(tile[tx][ty + 8 * yy]);
}

// init: value <- bc2, barrier counters <- 0
__global__ void init_misc(float* __restrict__ v, const float* __restrict__ bc2,
                          unsigned* __restrict__ bar) {
    int i = blockIdx.x * blockDim.x + threadIdx.x;
    if (i < MROWS) v[i] = bc2[0];
    if (i < 2048) bar[i] = 0u;
}

// ---------------- generic 64x64 MFMA GEMM: C = A @ B (+epilogues) --------
template <int K, int EPI, bool AF32>
__global__ __launch_bounds__(256) void gemm64(
    const void* __restrict__ Aptr, const ushort_t* __restrict__ BT,
    const float* __restrict__ bias, ushort_t* __restrict__ Cout, int ldc,
    const float* __restrict__ wc2, float* __restrict__ value) {
    __shared__ __align__(16) ushort_t Als[64][40];
    __shared__ __align__(16) ushort_t Bls[64][40];
    int tid = threadIdx.x;
    int wave = tid >> 6, lane = tid & 63, quad = lane >> 4, l16 = lane & 15;
    int bm = blockIdx.x * 64, bn = blockIdx.y * 64;
    int lrow = tid >> 2, lk = (tid & 3) * 8;

    f32x4 acc[4];
    for (int c = 0; c < 4; ++c) acc[c] = (f32x4){0.f, 0.f, 0.f, 0.f};

    for (int k0 = 0; k0 < K; k0 += 32) {
        if constexpr (AF32) {
            const float* A = (const float*)Aptr;
            const float4* pa =
                (const float4*)&A[(size_t)(bm + lrow) * K + k0 + lk];
            float4 a0 = pa[0], a1 = pa[1];
            ushort_t* d = &Als[lrow][lk];
            d[0] = f2bf(a0.x); d[1] = f2bf(a0.y); d[2] = f2bf(a0.z); d[3] = f2bf(a0.w);
            d[4] = f2bf(a1.x); d[5] = f2bf(a1.y); d[6] = f2bf(a1.z); d[7] = f2bf(a1.w);
        } else {
            const ushort_t* A = (const ushort_t*)Aptr;
            *(bf16x8*)&Als[lrow][lk] =
                *(const bf16x8*)&A[(size_t)(bm + lrow) * K + k0 + lk];
        }
        *(bf16x8*)&Bls[lrow][lk] =
            *(const bf16x8*)&BT[(size_t)(bn + lrow) * K + k0 + lk];
        __syncthreads();
        bf16x8 a = *(const bf16x8*)&Als[16 * wave + l16][quad * 8];
        for (int c = 0; c < 4; ++c) {
            bf16x8 b = *(const bf16x8*)&Bls[16 * c + l16][quad * 8];
            acc[c] = __builtin_amdgcn_mfma_f32_16x16x32_bf16(a, b, acc[c], 0, 0, 0);
        }
        __syncthreads();
    }

    int row_l = 16 * wave + 4 * quad;
    if constexpr (EPI == 0 || EPI == 1) {
        for (int c = 0; c < 4; ++c) {
            int col = bn + 16 * c + l16;
            float bv = bias[col];
            for (int i = 0; i < 4; ++i) {
                float v = acc[c][i] + bv;
                if constexpr (EPI == 0) v = fmaxf(v, 0.f);
                Cout[(size_t)(bm + row_l + i) * ldc + col] = f2bf(v);
            }
        }
    } else {
        float s[4] = {0.f, 0.f, 0.f, 0.f};
        for (int c = 0; c < 4; ++c) {
            int col = bn + 16 * c + l16;
            float bv = bias[col], w2 = wc2[col];
            for (int i = 0; i < 4; ++i)
                s[i] += fmaxf(acc[c][i] + bv, 0.f) * w2;
        }
        for (int i = 0; i < 4; ++i) {
            float v = s[i];
            v += __shfl_xor(v, 1);
            v += __shfl_xor(v, 2);
            v += __shfl_xor(v, 4);
            v += __shfl_xor(v, 8);
            if (l16 == 0) atomicAdd(&value[bm + row_l + i], v);
        }
    }
}

// ---------------- rowwise LayerNorm over H=512, in-place on bf16 --------
__global__ __launch_bounds__(256) void ln_kernel(ushort_t* __restrict__ emb,
                                                 const float* __restrict__ scale,
                                                 const float* __restrict__ biasv) {
    int wave = threadIdx.x >> 6, lane = threadIdx.x & 63;
    size_t row = (size_t)blockIdx.x * 4 + wave;
    ushort_t* p = &emb[row * HD + lane * 8];
    bf16x8 xv = *(const bf16x8*)p;
    float x[8];
    float sum = 0.f, sq = 0.f;
    for (int j = 0; j < 8; ++j) {
        x[j] = bf2f((ushort_t)xv[j]);
        sum += x[j];
        sq += x[j] * x[j];
    }
    for (int off = 32; off > 0; off >>= 1) {
        sum += __shfl_xor(sum, off);
        sq += __shfl_xor(sq, off);
    }
    float mean = sum * (1.f / 512.f);
    float var = fmaxf(sq * (1.f / 512.f) - mean * mean, 0.f);
    float inv = rsqrtf(var + 1e-6f);
    bf16x8 ov;
    for (int j = 0; j < 8; ++j) {
        int col = lane * 8 + j;
        ov[j] = (short)f2bf((x[j] - mean) * inv * scale[col] + biasv[col]);
    }
    *(bf16x8*)p = ov;
}

// ---------------- GRU scan: persistent 256 blocks, LDS Wh, fence-free ---
// bg = bid&7 (XCD-local groups under bid%8 heuristic — perf only, not
// correctness), cg = bid>>3. Block owns rows [bg*64,+64) x cols [cg*16,+16).
// Wh slice in LDS. h ping-pong via sc0+sc1 (agent-coherent, L2-bypass)
// loads/stores. a-frags: ONE asm block of 16 global_load_dwordx4 sc0 sc1
// + s_waitcnt inside — compiler cannot serialize; 1 L3 latency total.
__global__ __launch_bounds__(256, 1) void scan_coop(
    const float* __restrict__ hidden, const int* __restrict__ dones,
    const ushort_t* __restrict__ WhT, const float* __restrict__ bhn,
    const ushort_t* __restrict__ xproj, ushort_t* __restrict__ ys,
    float* __restrict__ hlast, ushort_t* hb0, ushort_t* hb1,
    unsigned* bar) {
    __shared__ __align__(16) ushort_t Wls[48][520];   // 49,920 B
    int tid = threadIdx.x;
    int wave = tid >> 6, lane = tid & 63, quad = lane >> 4, l16 = lane & 15;
    int bid = blockIdx.x;
    int bg = bid & 7, cg = bid >> 3;
    int row0 = bg * 64 + wave * 16;   // this wave's 16 batch rows
    int col0 = cg * 16;               // this block's 16 h-cols

    // ---- stage Wh slice into LDS: row c = gate(c>>4), local col (c&15) ----
    for (int idx = tid; idx < 48 * 64; idx += 256) {
        int c = idx >> 6, ck = (idx & 63) * 8;
        int g = c >> 4, lc = c & 15;
        *(bf16x8*)&Wls[c][ck] =
            *(const bf16x8*)&WhT[(size_t)(g * 512 + col0 + lc) * 512 + ck];
    }

    // ---- fp32 master h (C-layout: col=l16, row=quad*4+i), done(0)-masked --
    float mast[4];
    int rbase = row0 + quad * 4;
#pragma unroll
    for (int i = 0; i < 4; ++i) {
        float h0 = hidden[(size_t)(rbase + i) * HD + col0 + l16];
        mast[i] = dones[rbase + i] ? 0.f : h0;   // dones[0*BATCH + r]
    }
    float bhnv = bhn[col0 + l16];

    unsigned* cnt = &bar[bg * 256];   // 8 sub-counters, 128 B apart
    unsigned* mycnt = &cnt[(cg & 7) * 32];

    // ---- publish(0) into hb0 ----
#pragma unroll
    for (int i = 0; i < 4; ++i) {
        unsigned u = f2bf(mast[i]);
        unsigned p1 = __shfl_xor((int)u, 1);
        unsigned u32 = u | (p1 << 16);
        unsigned hi = __shfl_xor((int)u32, 2);
        if ((l16 & 3) == 0) {
            unsigned long long q =
                (unsigned long long)u32 | ((unsigned long long)hi << 32);
            __hip_atomic_store(
                (unsigned long long*)&hb0[(size_t)(rbase + i) * HD + col0 + l16],
                q, __ATOMIC_RELAXED, __HIP_MEMORY_SCOPE_AGENT);
        }
    }
    // prefetch xproj(0) and dones(1)
    float xr[4], xz[4], xn[4];
    int dn_nxt[4];
#pragma unroll
    for (int i = 0; i < 4; ++i) {
        size_t m = (size_t)(rbase + i);
        const ushort_t* xp = &xproj[m * 1536 + col0 + l16];
        xr[i] = bf2f(xp[0]);
        xz[i] = bf2f(xp[512]);
        xn[i] = bf2f(xp[1024]);
        dn_nxt[i] = dones[BATCH + rbase + i];
    }
    __builtin_amdgcn_s_waitcnt(0);   // publishes acked at coherent pt; LDS done
    __syncthreads();
    if (tid == 0)
        __hip_atomic_fetch_add(mycnt, 1u, __ATOMIC_RELAXED,
                               __HIP_MEMORY_SCOPE_AGENT);

    for (int t = 0; t < T_STEPS; ++t) {
        // ---- barrier wait: all 32 group blocks published step t ----
        if (tid == 0) {
            unsigned target = 32u * (unsigned)(t + 1);
            for (;;) {
                unsigned s = 0;
#pragma unroll
                for (int c = 0; c < 8; ++c)
                    s += __hip_atomic_load(&cnt[c * 32], __ATOMIC_RELAXED,
                                           __HIP_MEMORY_SCOPE_AGENT);
                if (s >= target) break;
                __builtin_amdgcn_s_sleep(1);
            }
        }
        __syncthreads();
        asm volatile("" ::: "memory");
        ushort_t* rbuf = (t & 1) ? hb1 : hb0;
        ushort_t* wnext = (t & 1) ? hb0 : hb1;

        // ---- a-frags: one asm batch, 16 independent 16B sc0+sc1 loads,
        //      single waitcnt inside the block (no compiler serialization)
        bf16x8 afr[16];
        {
            const ushort_t* ap =
                &rbuf[(size_t)(row0 + l16) * HD + quad * 8];
            asm volatile(
                "global_load_dwordx4 %0, %16, off sc0 sc1\n\t"
                "global_load_dwordx4 %1, %16, off offset:64 sc0 sc1\n\t"
                "global_load_dwordx4 %2, %16, off offset:128 sc0 sc1\n\t"
                "global_load_dwordx4 %3, %16, off offset:192 sc0 sc1\n\t"
                "global_load_dwordx4 %4, %16, off offset:256 sc0 sc1\n\t"
                "global_load_dwordx4 %5, %16, off offset:320 sc0 sc1\n\t"
                "global_load_dwordx4 %6, %16, off offset:384 sc0 sc1\n\t"
                "global_load_dwordx4 %7, %16, off offset:448 sc0 sc1\n\t"
                "global_load_dwordx4 %8, %16, off offset:512 sc0 sc1\n\t"
                "global_load_dwordx4 %9, %16, off offset:576 sc0 sc1\n\t"
                "global_load_dwordx4 %10, %16, off offset:640 sc0 sc1\n\t"
                "global_load_dwordx4 %11, %16, off offset:704 sc0 sc1\n\t"
                "global_load_dwordx4 %12, %16, off offset:768 sc0 sc1\n\t"
                "global_load_dwordx4 %13, %16, off offset:832 sc0 sc1\n\t"
                "global_load_dwordx4 %14, %16, off offset:896 sc0 sc1\n\t"
                "global_load_dwordx4 %15, %16, off offset:960 sc0 sc1\n\t"
                "s_waitcnt vmcnt(0)"
                : "=&v"(afr[0]), "=&v"(afr[1]), "=&v"(afr[2]), "=&v"(afr[3]),
                  "=&v"(afr[4]), "=&v"(afr[5]), "=&v"(afr[6]), "=&v"(afr[7]),
                  "=&v"(afr[8]), "=&v"(afr[9]), "=&v"(afr[10]), "=&v"(afr[11]),
                  "=&v"(afr[12]), "=&v"(afr[13]), "=&v"(afr[14]), "=&v"(afr[15])
                : "v"(ap)
                : "memory");
        }
        f32x4 aR = (f32x4){0.f, 0.f, 0.f, 0.f};
        f32x4 aZ = (f32x4){0.f, 0.f, 0.f, 0.f};
        f32x4 aN = (f32x4){0.f, 0.f, 0.f, 0.f};
#pragma unroll
        for (int kt = 0; kt < 16; ++kt) {
            bf16x8 bR = *(const bf16x8*)&Wls[l16][kt * 32 + quad * 8];
            bf16x8 bZ = *(const bf16x8*)&Wls[16 + l16][kt * 32 + quad * 8];
            bf16x8 bN = *(const bf16x8*)&Wls[32 + l16][kt * 32 + quad * 8];
            aR = __builtin_amdgcn_mfma_f32_16x16x32_bf16(afr[kt], bR, aR, 0, 0, 0);
            aZ = __builtin_amdgcn_mfma_f32_16x16x32_bf16(afr[kt], bZ, aZ, 0, 0, 0);
            aN = __builtin_amdgcn_mfma_f32_16x16x32_bf16(afr[kt], bN, aN, 0, 0, 0);
        }

        // ---- gates; pack hnew 4 lanes->8B once, reuse for publish & ys ----
        unsigned long long qpk[4];
        float hnew[4];
#pragma unroll
        for (int i = 0; i < 4; ++i) {
            float r = fsigmoid(xr[i] + aR[i]);
            float z = fsigmoid(xz[i] + aZ[i]);
            float n = ftanh(xn[i] + r * (aN[i] + bhnv));
            hnew[i] = (1.f - z) * n + z * mast[i];
            unsigned u = f2bf(hnew[i]);
            unsigned p1 = __shfl_xor((int)u, 1);
            unsigned u32 = u | (p1 << 16);
            unsigned hi = __shfl_xor((int)u32, 2);
            qpk[i] = (unsigned long long)u32 | ((unsigned long long)hi << 32);
            mast[i] = (t < T_STEPS - 1 && dn_nxt[i]) ? 0.f : hnew[i];
        }
        if (t < T_STEPS - 1 && (l16 & 3) == 0) {
#pragma unroll
            for (int i = 0; i < 4; ++i) {
                unsigned long long qp = dn_nxt[i] ? 0ull : qpk[i];
                __hip_atomic_store(
                    (unsigned long long*)&wnext[(size_t)(rbase + i) * HD +
                                                col0 + l16],
                    qp, __ATOMIC_RELAXED, __HIP_MEMORY_SCOPE_AGENT);
            }
        }
        asm volatile("" ::: "memory");
        __builtin_amdgcn_s_waitcnt(0);   // drain publishes
        // ---- ys stores (packed 8B) + next-step prefetch: overlap poll ----
        if ((l16 & 3) == 0) {
#pragma unroll
            for (int i = 0; i < 4; ++i) {
                size_t m = (size_t)t * BATCH + rbase + i;
                *(unsigned long long*)&ys[m * HD + col0 + l16] = qpk[i];
            }
        }
        if (t < T_STEPS - 1) {
            int tn = t + 1;
            int td = (t + 2 < T_STEPS) ? t + 2 : T_STEPS - 1;
#pragma unroll
            for (int i = 0; i < 4; ++i) {
                size_t m = (size_t)tn * BATCH + rbase + i;
                const ushort_t* xp = &xproj[m * 1536 + col0 + l16];
                xr[i] = bf2f(xp[0]);
                xz[i] = bf2f(xp[512]);
                xn[i] = bf2f(xp[1024]);
                dn_nxt[i] = dones[td * BATCH + rbase + i];
            }
        }
        asm volatile("" ::: "memory");   // pin prefetch above arrive/poll
        __syncthreads();
        if (tid == 0 && t < T_STEPS - 1)
            __hip_atomic_fetch_add(mycnt, 1u, __ATOMIC_RELAXED,
                                   __HIP_MEMORY_SCOPE_AGENT);
    }
#pragma unroll
    for (int i = 0; i < 4; ++i)
        hlast[(size_t)(rbase + i) * HD + col0 + l16] = mast[i];
}

extern "C" void kernel_launch(void* const* d_in, const int* in_sizes, int n_in,
                              void* d_out, int out_size, void* d_ws,
                              size_t ws_size, hipStream_t stream) {
    const float* hidden      = (const float*)d_in[0];
    const float* world_state = (const float*)d_in[1];
    const int*   dones       = (const int*)d_in[2];
    const float* Wd  = (const float*)d_in[3];
    const float* bd  = (const float*)d_in[4];
    const float* lns = (const float*)d_in[5];
    const float* lnb = (const float*)d_in[6];
    const float* Wi  = (const float*)d_in[7];
    const float* bi  = (const float*)d_in[8];
    const float* Wh  = (const float*)d_in[9];
    const float* bhn = (const float*)d_in[10];
    const float* Wc1 = (const float*)d_in[11];
    const float* bc1 = (const float*)d_in[12];
    const float* Wc2 = (const float*)d_in[13];
    const float* bc2 = (const float*)d_in[14];

    float* out_h = (float*)d_out;            // h_last [512,512]
    float* out_v = out_h + BATCH * HD;       // value  [128,512]

    char* ws = (char*)d_ws;
    ushort_t* WdT   = (ushort_t*)(ws + 0);            // [512][1024]
    ushort_t* WiT   = (ushort_t*)(ws + 1048576);      // [1536][512]
    ushort_t* WhT   = (ushort_t*)(ws + 2621440);      // [1536][512]
    ushort_t* Wc1T  = (ushort_t*)(ws + 4194304);      // [512][512]
    unsigned* bar   = (unsigned*)(ws + 4718592);      // 2048 uints (8 KB)
    ushort_t* hb0   = (ushort_t*)(ws + 4726784);      // [512][512] bf16
    ushort_t* hb1   = (ushort_t*)(ws + 5251072);      // [512][512] bf16
    ushort_t* xproj = (ushort_t*)(ws + 8388608);      // [65536][1536] bf16
    ushort_t* emb   = (ushort_t*)(ws + 209715200);    // [65536][512] bf16
    ushort_t* ysb   = emb;  // reuse: emb dead after gemm2, ys written by scan

    dim3 tb(32, 8);
    transpose_to_bf16<<<dim3(16, 32), tb, 0, stream>>>(Wd, WdT, OBSD, HD);
    transpose_to_bf16<<<dim3(48, 16), tb, 0, stream>>>(Wi, WiT, HD, 1536);
    transpose_to_bf16<<<dim3(48, 16), tb, 0, stream>>>(Wh, WhT, HD, 1536);
    transpose_to_bf16<<<dim3(16, 16), tb, 0, stream>>>(Wc1, Wc1T, HD, FCD);
    init_misc<<<256, 256, 0, stream>>>(out_v, bc2, bar);

    // emb = relu(world_state @ Wd + bd)
    gemm64<OBSD, 0, true><<<dim3(MROWS / 64, HD / 64), 256, 0, stream>>>(
        world_state, WdT, bd, emb, HD, nullptr, nullptr);
    // LayerNorm in place
    ln_kernel<<<MROWS / 4, 256, 0, stream>>>(emb, lns, lnb);
    // xproj = emb @ Wi + bi
    gemm64<HD, 1, false><<<dim3(MROWS / 64, 1536 / 64), 256, 0, stream>>>(
        emb, WiT, bi, xproj, 1536, nullptr, nullptr);
    // persistent GRU scan: 256 blocks, bg=bid&7 XCD-local groups, LDS Wh,
    // batched-asm a-frag loads (1 L3 latency/step)
    scan_coop<<<dim3(256), dim3(256), 0, stream>>>(
        hidden, dones, WhT, bhn, xproj, ysb, out_h, hb0, hb1, bar);
    // value = relu(ys @ Wc1 + bc1) @ Wc2 + bc2
    gemm64<HD, 2, false><<<dim3(MROWS / 64, FCD / 64), 256, 0, stream>>>(
        ysb, Wc1T, bc1, nullptr, 0, Wc2, out_v);
}